// Round 4
// baseline (376.647 us; speedup 1.0000x reference)
//
#include <hip/hip_runtime.h>

// ImageReconstruction: unfold -> soft-VQ softmax(35*(2ab - b2)) over 256 codes
// -> sparse reconstruct -> fold, + choice penalty (sum min(w,1-w) / N).
//
// Round-5: round-4 still spilled (~25 regs: WRITE 254MB vs 66 ideal, VGPR=48):
// at (256,5) the ~96-reg budget minus 32 AGPRs (acc[8]) leaves 48 arch VGPRs
// vs ~75 live. Fix: QUARTER-split (64 codes/pass) -> acc[4] = 16 AGPRs ->
// ~80 arch VGPRs available, ~60 live -> no spill at 5 waves/SIMD.
//  * 2-deep DMA double-buffer (16KB x2): quarter k+1 always in flight via
//    global_load_lds; counted s_waitcnt vmcnt(4) at loop head (T4), issue
//    quarter k+2 right after the reads-done barrier (T14).
//  * Merged (Ah+Al)*Bh + Ah*Bl GEMM per quarter: 24 mfma x4 = 96 (unchanged).
//  * Online softmax across 4 quarters; rr-rescale skipped when the running
//    max didn't move (T13-style __any guard).
//  * Penalty closed form (w_max = 1/S), invS at writeout, INV_N in atomic,
//    pre-swizzled B source (linear DMA dest + swizzled LDS read) - all
//    validated rounds 3-4.
//  * Barriers: 7; LDS 32768B -> 5 blocks/CU exactly at (256,5).

typedef short short8 __attribute__((ext_vector_type(8)));
typedef float floatx4 __attribute__((ext_vector_type(4)));

namespace {
constexpr float BETA_C = 35.0f;
constexpr float TAU    = 1e-6f;
constexpr float INV_N  = 1.0f / 262144.0f;
constexpr size_t IMG_ELEMS = (size_t)64 * 512 * 512;
// Two quarter buffers, each: Bh [0,2048) + Bl [2048,4096) words.
constexpr int WQ0 = 0;
constexpr int WQ1 = 4096;
constexpr int WR  = 0;      // recon f32 (reuses buffers after final bar): p*68+d
constexpr int WS  = 4352;   // invS per patch: [4352, 4416)
constexpr int NWORDS = 8192;   // 32768 B
}

__device__ __forceinline__ unsigned short f2bf(float x) {  // round-to-nearest
  unsigned u = __float_as_uint(x);
  return (unsigned short)((u + 0x7FFFu + ((u >> 16) & 1u)) >> 16);
}
__device__ __forceinline__ float bf2f(unsigned short h) {
  return __uint_as_float((unsigned)h << 16);
}
__device__ __forceinline__ unsigned pack2(unsigned short lo, unsigned short hi) {
  return (unsigned)lo | ((unsigned)hi << 16);
}
// A-split: hi = RNE bf16, lo = TRUNCATED bf16 of residual (err <= 2^-17 * a).
__device__ __forceinline__ void cvt8t(float4 a, float4 b, short8& h, short8& l) {
  float f[8] = {a.x, a.y, a.z, a.w, b.x, b.y, b.z, b.w};
#pragma unroll
  for (int i = 0; i < 8; ++i) {
    unsigned short hh = f2bf(f[i]);
    h[i] = (short)hh;
    float lf = f[i] - bf2f(hh);
    l[i] = (short)(__float_as_uint(lf) >> 16);
  }
}
// Async 16B global -> LDS (wave-uniform LDS base + lane*16; per-lane gsrc).
__device__ __forceinline__ void cp16(const uint4* g, unsigned* l) {
  __builtin_amdgcn_global_load_lds(
      (const __attribute__((address_space(1))) void*)g,
      (__attribute__((address_space(3))) void*)l, 16, 0, 0);
}

// Pre-kernel: split codebook into bf16 hi/lo granules, stored PRE-SWIZZLED
// (code c, granule g -> slot c*8 + (g ^ (c&7))), + per-code -BETA*||b||^2.
__global__ void pack_codes(const float* __restrict__ blk,
                           unsigned* __restrict__ wsBh,
                           unsigned* __restrict__ wsBl,
                           float* __restrict__ wsB2) {
  const int c = threadIdx.x;  // 256 threads, one code each
  const float* src = blk + c * 64;
  float b2 = 0.f;
#pragma unroll
  for (int g = 0; g < 8; ++g) {
    int slot = c * 8 + (g ^ (c & 7));
#pragma unroll
    for (int t = 0; t < 4; ++t) {
      float v0 = src[g * 8 + 2 * t], v1 = src[g * 8 + 2 * t + 1];
      b2 += v0 * v0 + v1 * v1;
      unsigned short h0 = f2bf(v0), h1 = f2bf(v1);
      unsigned short l0 = f2bf(v0 - bf2f(h0)), l1 = f2bf(v1 - bf2f(h1));
      wsBh[slot * 4 + t] = pack2(h0, h1);
      wsBl[slot * 4 + t] = pack2(l0, l1);
    }
  }
  wsB2[c] = -BETA_C * b2;
}

__global__ __launch_bounds__(256, 5) void recon_kernel(
    const float* __restrict__ img, const float* __restrict__ blk,
    const unsigned* __restrict__ wsBh, const unsigned* __restrict__ wsBl,
    const float* __restrict__ wsB2, float* __restrict__ out,
    float* __restrict__ penAcc) {
  __shared__ unsigned sMem[NWORDS];
  float* sMemF = reinterpret_cast<float*>(sMem);

  const int tid = threadIdx.x;
  const int lane = tid & 63;
  const int wave = tid >> 6;
  const int b = blockIdx.x >> 6;
  const int ht = blockIdx.x & 63;
  const int c15 = lane & 15;
  const int q = lane >> 4;

  const uint4* srcH = reinterpret_cast<const uint4*>(wsBh);
  const uint4* srcL = reinterpret_cast<const uint4*>(wsBl);

  // ---- A fragments direct from HBM (issue first, convert later) ----
  const float* imgBase = img + (size_t)b * (512 * 512) + (size_t)(ht * 8) * 512;
  const float* aptr = imgBase + q * 512 + (wave * 16 + c15) * 8;
  float4 v00 = *reinterpret_cast<const float4*>(aptr);
  float4 v01 = *reinterpret_cast<const float4*>(aptr + 4);
  float4 v10 = *reinterpret_cast<const float4*>(aptr + 2048);       // row q+4
  float4 v11 = *reinterpret_cast<const float4*>(aptr + 2048 + 4);

  // ---- issue quarter-0 -> buf0, quarter-1 -> buf1 (async DMA, 4 each) ----
#pragma unroll
  for (int i = 0; i < 2; ++i) {
    cp16(srcH + i * 256 + tid, &sMem[WQ0 + (i * 4 + wave) * 256]);
    cp16(srcL + i * 256 + tid, &sMem[WQ0 + 2048 + (i * 4 + wave) * 256]);
  }
#pragma unroll
  for (int i = 0; i < 2; ++i) {
    cp16(srcH + 512 + i * 256 + tid, &sMem[WQ1 + (i * 4 + wave) * 256]);
    cp16(srcL + 512 + i * 256 + tid, &sMem[WQ1 + 2048 + (i * 4 + wave) * 256]);
  }

  // ---- convert A to bf16 hi/lo fragments (overlaps DMA flight) ----
  short8 ah[2], al[2];
  cvt8t(v00, v01, ah[0], al[0]);   // k = 8q..8q+7
  cvt8t(v10, v11, ah[1], al[1]);   // k = 32+8q..39+8q

  // B-frag word offsets within a quarter buffer: in-quarter code cl = 16n+c15,
  // granules q and q^4, swizzle key cl&7 == c15&7 (pre-swizzled at pack time).
  const int kx = c15 & 7;
  const int off0 = (8 * c15 + (q ^ kx)) * 4;
  const int off1 = (8 * c15 + ((q ^ 4) ^ kx)) * 4;

  float m[4], sm[4];
  float rr[16] = {0.f, 0.f, 0.f, 0.f, 0.f, 0.f, 0.f, 0.f,
                  0.f, 0.f, 0.f, 0.f, 0.f, 0.f, 0.f, 0.f};

#pragma unroll
  for (int k = 0; k < 4; ++k) {
    const int W = (k & 1) ? WQ1 : WQ0;
    if (k < 3) asm volatile("s_waitcnt vmcnt(4)" ::: "memory");
    else       asm volatile("s_waitcnt vmcnt(0)" ::: "memory");
    __syncthreads();   // quarter k staged in all waves

    floatx4 acc[4];
#pragma unroll
    for (int n = 0; n < 4; ++n) acc[n] = (floatx4){0.f, 0.f, 0.f, 0.f};
    // ---- merged GEMM: (Ah+Al)*Bh + Ah*Bl, 24 mfma ----
#pragma unroll
    for (int n = 0; n < 4; ++n) {
      short8 b0h = *reinterpret_cast<const short8*>(&sMem[W + off0 + 512 * n]);
      short8 b1h = *reinterpret_cast<const short8*>(&sMem[W + off1 + 512 * n]);
      short8 b0l = *reinterpret_cast<const short8*>(&sMem[W + 2048 + off0 + 512 * n]);
      short8 b1l = *reinterpret_cast<const short8*>(&sMem[W + 2048 + off1 + 512 * n]);
      acc[n] = __builtin_amdgcn_mfma_f32_16x16x32_bf16(ah[0], b0h, acc[n], 0, 0, 0);
      acc[n] = __builtin_amdgcn_mfma_f32_16x16x32_bf16(al[0], b0h, acc[n], 0, 0, 0);
      acc[n] = __builtin_amdgcn_mfma_f32_16x16x32_bf16(ah[1], b1h, acc[n], 0, 0, 0);
      acc[n] = __builtin_amdgcn_mfma_f32_16x16x32_bf16(al[1], b1h, acc[n], 0, 0, 0);
      acc[n] = __builtin_amdgcn_mfma_f32_16x16x32_bf16(ah[0], b0l, acc[n], 0, 0, 0);
      acc[n] = __builtin_amdgcn_mfma_f32_16x16x32_bf16(ah[1], b1l, acc[n], 0, 0, 0);
    }
    if (k < 2) {
      __syncthreads();   // all waves done reading buf W
      // issue quarter k+2 into W; flight hides under this quarter's epilogue
#pragma unroll
      for (int i = 0; i < 2; ++i) {
        cp16(srcH + (k + 2) * 512 + i * 256 + tid, &sMem[W + (i * 4 + wave) * 256]);
        cp16(srcL + (k + 2) * 512 + i * 256 + tid, &sMem[W + 2048 + (i * 4 + wave) * 256]);
      }
    }

    // ---- logits (col=c15 -> code 64k+16n+c15, row=4q+r -> patch) ----
#pragma unroll
    for (int n = 0; n < 4; ++n) {
      float b2s = wsB2[64 * k + 16 * n + c15];   // == -BETA*||b||^2
#pragma unroll
      for (int r = 0; r < 4; ++r)
        acc[n][r] = fmaf(2.0f * BETA_C, acc[n][r], b2s);
    }
    // ---- quarter max (reduce over n, then c15 lanes) ----
    float M[4];
#pragma unroll
    for (int r = 0; r < 4; ++r) {
      float mm = fmaxf(fmaxf(acc[0][r], acc[1][r]), fmaxf(acc[2][r], acc[3][r]));
#pragma unroll
      for (int off = 1; off <= 8; off <<= 1) mm = fmaxf(mm, __shfl_xor(mm, off, 64));
      M[r] = mm;
    }
    if (k == 0) {
#pragma unroll
      for (int r = 0; r < 4; ++r) { m[r] = M[r]; sm[r] = 0.f; }
    } else {
      float scl[4];
#pragma unroll
      for (int r = 0; r < 4; ++r) {
        float mn = fmaxf(m[r], M[r]);
        scl[r] = __expf(m[r] - mn);    // 1.0 when max unchanged
        m[r] = mn;
        sm[r] *= scl[r];
      }
      // rescale rr only if some patch's max moved (wave-uniform guard)
      bool moved = (scl[0] < 1.f) | (scl[1] < 1.f) | (scl[2] < 1.f) | (scl[3] < 1.f);
      if (__any(moved)) {
        // patch 4*qq+r's scale lives in lanes with q==qq
#pragma unroll
        for (int qq = 0; qq < 4; ++qq)
#pragma unroll
          for (int r = 0; r < 4; ++r) {
            float sq = __shfl(scl[r], qq * 16 + c15, 64);
            rr[4 * qq + r] *= sq;
          }
      }
    }
    // ---- exp numerators + partial (per-lane) sum ----
#pragma unroll
    for (int n = 0; n < 4; ++n)
#pragma unroll
      for (int r = 0; r < 4; ++r) {
        float e = __expf(acc[n][r] - m[r]);
        acc[n][r] = e;
        sm[r] += e;
      }
    // ---- sparse scan: 1 ballot per 16-code tile ----
#pragma unroll
    for (int n = 0; n < 4; ++n) {
      float em = fmaxf(fmaxf(acc[n][0], acc[n][1]), fmaxf(acc[n][2], acc[n][3]));
      unsigned long long msk = __ballot(em > TAU);
      while (msk) {                  // near-one-hot: ~1-2 iterations
        int L = __builtin_ctzll(msk);
        msk &= msk - 1;
        float w0 = __uint_as_float(__builtin_amdgcn_readlane(__float_as_uint(acc[n][0]), L));
        float w1 = __uint_as_float(__builtin_amdgcn_readlane(__float_as_uint(acc[n][1]), L));
        float w2 = __uint_as_float(__builtin_amdgcn_readlane(__float_as_uint(acc[n][2]), L));
        float w3 = __uint_as_float(__builtin_amdgcn_readlane(__float_as_uint(acc[n][3]), L));
        float bv = blk[(size_t)(64 * k + 16 * n + (L & 15)) * 64 + lane];
        switch (L >> 4) {            // contributor's q (uniform scalar branch)
          case 0: rr[0] += w0 * bv;  rr[1] += w1 * bv;  rr[2] += w2 * bv;  rr[3] += w3 * bv;  break;
          case 1: rr[4] += w0 * bv;  rr[5] += w1 * bv;  rr[6] += w2 * bv;  rr[7] += w3 * bv;  break;
          case 2: rr[8] += w0 * bv;  rr[9] += w1 * bv;  rr[10] += w2 * bv; rr[11] += w3 * bv; break;
          default: rr[12] += w0 * bv; rr[13] += w1 * bv; rr[14] += w2 * bv; rr[15] += w3 * bv; break;
        }
      }
    }
  }

  // ---- final denominator + invS + penalty (closed form from S only) ----
  float invS[4];
#pragma unroll
  for (int r = 0; r < 4; ++r) {
#pragma unroll
    for (int off = 1; off <= 8; off <<= 1) sm[r] += __shfl_xor(sm[r], off, 64);
    invS[r] = 1.0f / sm[r];
  }
  float pen = 0.f;
  if (c15 == 0) {
#pragma unroll
    for (int r = 0; r < 4; ++r)
      // sum_k min(w,1-w) = 1 + [w_max>1/2](1-2*w_max), w_max = invS exactly
      pen += (invS[r] > 0.5f) ? (2.0f - 2.0f * invS[r]) : 1.0f;
  }
  pen += __shfl_xor(pen, 16, 64);   // only lanes 0,16,32,48 are nonzero
  pen += __shfl_xor(pen, 32, 64);
  if (lane == 0) atomicAdd(penAcc, pen * INV_N);

  __syncthreads();  // all B reads done -> region reusable as recon

  // ---- stage invS + recon (d = lane); readers are same-wave (lgkmcnt) ----
  if (c15 == 0) {
#pragma unroll
    for (int r = 0; r < 4; ++r)
      sMemF[WS + wave * 16 + 4 * q + r] = invS[r];
  }
#pragma unroll
  for (int pl = 0; pl < 16; ++pl)
    sMemF[WR + (wave * 16 + pl) * 68 + lane] = rr[pl];
  // wave w owns cols [128w, 128w+128) of the 8x512 strip
  float* outBase = out + (size_t)b * (512 * 512) + (size_t)(ht * 8) * 512 +
                   wave * 128;
#pragma unroll
  for (int i = 0; i < 4; ++i) {
    int f = i * 64 + lane;          // float4-chunk id in wave's 8x128 stripe
    int row = f >> 5;               // 0..7
    int cc = f & 31;                // float4 col within stripe
    int wtl = cc >> 1, hw = cc & 1;
    float4 v = *reinterpret_cast<const float4*>(
        &sMemF[WR + (wave * 16 + wtl) * 68 + row * 8 + hw * 4]);
    float is = sMemF[WS + wave * 16 + wtl];
    v.x *= is; v.y *= is; v.z *= is; v.w *= is;
    *reinterpret_cast<float4*>(outBase + row * 512 + cc * 4) = v;
  }
}

extern "C" void kernel_launch(void* const* d_in, const int* in_sizes, int n_in,
                              void* d_out, int out_size, void* d_ws, size_t ws_size,
                              hipStream_t stream) {
  const float* img = (const float*)d_in[0];   // (64,1,512,512) fp32
  const float* blk = (const float*)d_in[1];   // (256,8,8) fp32
  float* out = (float*)d_out;
  float* penSlot = out + IMG_ELEMS;

  unsigned* wsBh = (unsigned*)d_ws;           // 32 KB (pre-swizzled)
  unsigned* wsBl = wsBh + 8192;               // 32 KB (pre-swizzled)
  float* wsB2 = (float*)(wsBl + 8192);        // 1 KB (-BETA*||b||^2)

  pack_codes<<<dim3(1), dim3(256), 0, stream>>>(blk, wsBh, wsBl, wsB2);
  hipMemsetAsync(penSlot, 0, sizeof(float), stream);
  recon_kernel<<<dim3(4096), dim3(256), 0, stream>>>(img, blk, wsBh, wsBl,
                                                     wsB2, out, penSlot);
}

// Round 5
// 326.361 us; speedup vs baseline: 1.1541x; 1.1541x over previous
//
#include <hip/hip_runtime.h>

// ImageReconstruction: unfold -> soft-VQ softmax(35*(2ab - b2)) over 256 codes
// -> sparse reconstruct -> fold, + choice penalty (sum min(w,1-w) / N).
//
// Round-6: rounds 3-5 showed (256,5) ALWAYS spills: VGPR_Count pinned at 48
// whether acc is 32 or 16 AGPRs -> allocator splits the ~102-reg unified
// budget ~50/50 arch/AGPR when MFMA present; arch live (~65) >> 48.
// Round 1 proved the same live set fits at (256,4): VGPR=64, WRITE=66MB
// (zero scratch). So: round-3's half-split DMA pipeline at (256,4).
//  * B staging via global_load_lds (16B, zero staging VGPRs); pack_codes
//    writes XOR-swizzled order so DMA dest is linear, LDS read swizzled
//    (validated rounds 3-5, absmax 0.0039).
//  * Bh+Bl of a code-half in two 16KB LDS buffers -> ONE merged 48-mfma
//    GEMM loop per half; 4 barriers total.
//  * Half-1 DMA issued after the reads-done barrier; flight hides under
//    half-0's softmax/scan epilogue (T14).
//  * Penalty closed form (w_max = 1/S), invS at writeout, INV_N in atomic.
//  * pack_codes parallelized: 8 blocks x 256 threads, one granule/thread
//    (was 1 block doing 64 elems/thread serially).
//  * acc[8] = 32 AGPR <= 64 AGPR-side budget; arch ~64 -> no spill.

typedef short short8 __attribute__((ext_vector_type(8)));
typedef float floatx4 __attribute__((ext_vector_type(4)));

namespace {
constexpr float BETA_C = 35.0f;
constexpr float TAU    = 1e-6f;
constexpr float INV_N  = 1.0f / 262144.0f;
constexpr size_t IMG_ELEMS = (size_t)64 * 512 * 512;
constexpr int WB0 = 0;      // Bh of current half: words [0, 4096)
constexpr int WB1 = 4096;   // Bl of current half: words [4096, 8192)
constexpr int WR  = 0;      // recon f32 (reuses buffers after final bar): p*68+d
constexpr int WS  = 4352;   // invS per patch: [4352, 4416)
constexpr int NWORDS = 8192;   // 32768 B
}

__device__ __forceinline__ unsigned short f2bf(float x) {  // round-to-nearest
  unsigned u = __float_as_uint(x);
  return (unsigned short)((u + 0x7FFFu + ((u >> 16) & 1u)) >> 16);
}
__device__ __forceinline__ float bf2f(unsigned short h) {
  return __uint_as_float((unsigned)h << 16);
}
__device__ __forceinline__ unsigned pack2(unsigned short lo, unsigned short hi) {
  return (unsigned)lo | ((unsigned)hi << 16);
}
// A-split: hi = RNE bf16, lo = TRUNCATED bf16 of residual (err <= 2^-17 * a).
__device__ __forceinline__ void cvt8t(float4 a, float4 b, short8& h, short8& l) {
  float f[8] = {a.x, a.y, a.z, a.w, b.x, b.y, b.z, b.w};
#pragma unroll
  for (int i = 0; i < 8; ++i) {
    unsigned short hh = f2bf(f[i]);
    h[i] = (short)hh;
    float lf = f[i] - bf2f(hh);
    l[i] = (short)(__float_as_uint(lf) >> 16);
  }
}
// Async 16B global -> LDS (wave-uniform LDS base + lane*16; per-lane gsrc).
__device__ __forceinline__ void cp16(const uint4* g, unsigned* l) {
  __builtin_amdgcn_global_load_lds(
      (const __attribute__((address_space(1))) void*)g,
      (__attribute__((address_space(3))) void*)l, 16, 0, 0);
}

// Pre-kernel: split codebook into bf16 hi/lo granules, stored PRE-SWIZZLED
// (code c, granule g -> slot c*8 + (g ^ (c&7))), + per-code -BETA*||b||^2.
// One granule (8 floats) per thread: 2048 threads = 8 blocks.
__global__ void pack_codes(const float* __restrict__ blk,
                           unsigned* __restrict__ wsBh,
                           unsigned* __restrict__ wsBl,
                           float* __restrict__ wsB2) {
  const int gid = blockIdx.x * 256 + threadIdx.x;   // 0..2047
  const int c = gid >> 3, g = gid & 7;
  const float* src = blk + c * 64 + g * 8;
  float4 a = *reinterpret_cast<const float4*>(src);
  float4 b = *reinterpret_cast<const float4*>(src + 4);
  float f[8] = {a.x, a.y, a.z, a.w, b.x, b.y, b.z, b.w};
  uint4 ph, pl;
  unsigned* phw = reinterpret_cast<unsigned*>(&ph);
  unsigned* plw = reinterpret_cast<unsigned*>(&pl);
  float b2 = 0.f;
#pragma unroll
  for (int t = 0; t < 4; ++t) {
    float v0 = f[2 * t], v1 = f[2 * t + 1];
    b2 += v0 * v0 + v1 * v1;
    unsigned short h0 = f2bf(v0), h1 = f2bf(v1);
    unsigned short l0 = f2bf(v0 - bf2f(h0)), l1 = f2bf(v1 - bf2f(h1));
    phw[t] = pack2(h0, h1);
    plw[t] = pack2(l0, l1);
  }
  const int slot = c * 8 + (g ^ (c & 7));
  reinterpret_cast<uint4*>(wsBh)[slot] = ph;
  reinterpret_cast<uint4*>(wsBl)[slot] = pl;
  // reduce b2 across the 8 lanes of this code (g = low 3 bits of lane)
  b2 += __shfl_xor(b2, 1, 64);
  b2 += __shfl_xor(b2, 2, 64);
  b2 += __shfl_xor(b2, 4, 64);
  if (g == 0) wsB2[c] = -BETA_C * b2;
}

__global__ __launch_bounds__(256, 4) void recon_kernel(
    const float* __restrict__ img, const float* __restrict__ blk,
    const unsigned* __restrict__ wsBh, const unsigned* __restrict__ wsBl,
    const float* __restrict__ wsB2, float* __restrict__ out,
    float* __restrict__ penAcc) {
  __shared__ unsigned sMem[NWORDS];
  float* sMemF = reinterpret_cast<float*>(sMem);

  const int tid = threadIdx.x;
  const int lane = tid & 63;
  const int wave = tid >> 6;
  const int b = blockIdx.x >> 6;
  const int ht = blockIdx.x & 63;
  const int c15 = lane & 15;
  const int q = lane >> 4;

  // ---- A fragments direct from HBM (issue first, convert later) ----
  const float* imgBase = img + (size_t)b * (512 * 512) + (size_t)(ht * 8) * 512;
  const float* aptr = imgBase + q * 512 + (wave * 16 + c15) * 8;
  float4 v00 = *reinterpret_cast<const float4*>(aptr);
  float4 v01 = *reinterpret_cast<const float4*>(aptr + 4);
  float4 v10 = *reinterpret_cast<const float4*>(aptr + 2048);       // row q+4
  float4 v11 = *reinterpret_cast<const float4*>(aptr + 2048 + 4);

  // ---- issue half-0 stages: Bh -> buf0, Bl -> buf1 (async DMA) ----
  const uint4* srcH = reinterpret_cast<const uint4*>(wsBh);
  const uint4* srcL = reinterpret_cast<const uint4*>(wsBl);
#pragma unroll
  for (int i = 0; i < 4; ++i) {
    cp16(srcH + i * 256 + tid, &sMem[WB0 + (i * 4 + wave) * 256]);
    cp16(srcL + i * 256 + tid, &sMem[WB1 + (i * 4 + wave) * 256]);
  }

  // ---- convert A to bf16 hi/lo fragments (overlaps DMA flight) ----
  short8 ah[2], al[2];
  cvt8t(v00, v01, ah[0], al[0]);   // k = 8q..8q+7
  cvt8t(v10, v11, ah[1], al[1]);   // k = 32+8q..39+8q

  asm volatile("s_waitcnt vmcnt(0)" ::: "memory");
  __syncthreads();  // bar1: half-0 B staged

  // B-frag addresses: in-half code cl = 16n+c15, granules q and q^4,
  // swizzle key cl&7 == c15&7 (pre-swizzled at pack time).
  const int kx = c15 & 7;
  const unsigned* pb0 = &sMem[(8 * c15 + (q ^ kx)) * 4];
  const unsigned* pb1 = &sMem[(8 * c15 + ((q ^ 4) ^ kx)) * 4];

  float m[4], sm[4];
  float rr[16] = {0.f, 0.f, 0.f, 0.f, 0.f, 0.f, 0.f, 0.f,
                  0.f, 0.f, 0.f, 0.f, 0.f, 0.f, 0.f, 0.f};

#pragma unroll
  for (int h = 0; h < 2; ++h) {
    floatx4 acc[8];
#pragma unroll
    for (int n = 0; n < 8; ++n) acc[n] = (floatx4){0.f, 0.f, 0.f, 0.f};
    // ---- merged GEMM: (Ah+Al)*Bh + Ah*Bl, 48 mfma ----
#pragma unroll
    for (int n = 0; n < 8; ++n) {
      short8 b0h = *reinterpret_cast<const short8*>(pb0 + 512 * n);
      short8 b1h = *reinterpret_cast<const short8*>(pb1 + 512 * n);
      short8 b0l = *reinterpret_cast<const short8*>(pb0 + WB1 + 512 * n);
      short8 b1l = *reinterpret_cast<const short8*>(pb1 + WB1 + 512 * n);
      acc[n] = __builtin_amdgcn_mfma_f32_16x16x32_bf16(ah[0], b0h, acc[n], 0, 0, 0);
      acc[n] = __builtin_amdgcn_mfma_f32_16x16x32_bf16(al[0], b0h, acc[n], 0, 0, 0);
      acc[n] = __builtin_amdgcn_mfma_f32_16x16x32_bf16(ah[1], b1h, acc[n], 0, 0, 0);
      acc[n] = __builtin_amdgcn_mfma_f32_16x16x32_bf16(al[1], b1h, acc[n], 0, 0, 0);
      acc[n] = __builtin_amdgcn_mfma_f32_16x16x32_bf16(ah[0], b0l, acc[n], 0, 0, 0);
      acc[n] = __builtin_amdgcn_mfma_f32_16x16x32_bf16(ah[1], b1l, acc[n], 0, 0, 0);
    }
    if (h == 0) {
      __syncthreads();  // bar2: all half-0 B reads done
      // issue half-1 stages; flight hides under the epilogue below
#pragma unroll
      for (int i = 0; i < 4; ++i) {
        cp16(srcH + 1024 + i * 256 + tid, &sMem[WB0 + (i * 4 + wave) * 256]);
        cp16(srcL + 1024 + i * 256 + tid, &sMem[WB1 + (i * 4 + wave) * 256]);
      }
    }

    // ---- logits (col=c15 -> code 128h+16n+c15, row=4q+r -> patch) ----
#pragma unroll
    for (int n = 0; n < 8; ++n) {
      float b2s = wsB2[128 * h + 16 * n + c15];   // == -BETA*||b||^2
#pragma unroll
      for (int r = 0; r < 4; ++r)
        acc[n][r] = fmaf(2.0f * BETA_C, acc[n][r], b2s);
    }
    // ---- half max (reduce over n, then c15 lanes) ----
    float M[4];
#pragma unroll
    for (int r = 0; r < 4; ++r) {
      float mm = acc[0][r];
#pragma unroll
      for (int n = 1; n < 8; ++n) mm = fmaxf(mm, acc[n][r]);
#pragma unroll
      for (int off = 1; off <= 8; off <<= 1) mm = fmaxf(mm, __shfl_xor(mm, off, 64));
      M[r] = mm;
    }
    if (h == 0) {
#pragma unroll
      for (int r = 0; r < 4; ++r) { m[r] = M[r]; sm[r] = 0.f; }
    } else {
      float scl[4];
#pragma unroll
      for (int r = 0; r < 4; ++r) {
        float mn = fmaxf(m[r], M[r]);
        scl[r] = __expf(m[r] - mn);    // 1.0 when max unchanged
        m[r] = mn;
        sm[r] *= scl[r];
      }
      // rescale rr only if some patch's max moved (wave-uniform guard)
      bool moved = (scl[0] < 1.f) | (scl[1] < 1.f) | (scl[2] < 1.f) | (scl[3] < 1.f);
      if (__any(moved)) {
        // patch 4*qq+r's scale lives in lanes with q==qq
#pragma unroll
        for (int qq = 0; qq < 4; ++qq)
#pragma unroll
          for (int r = 0; r < 4; ++r) {
            float sq = __shfl(scl[r], qq * 16 + c15, 64);
            rr[4 * qq + r] *= sq;
          }
      }
    }
    // ---- exp numerators + partial (per-lane) sum ----
#pragma unroll
    for (int n = 0; n < 8; ++n)
#pragma unroll
      for (int r = 0; r < 4; ++r) {
        float e = __expf(acc[n][r] - m[r]);
        acc[n][r] = e;
        sm[r] += e;
      }
    // ---- sparse scan: 1 ballot per 16-code tile ----
#pragma unroll
    for (int n = 0; n < 8; ++n) {
      float em = fmaxf(fmaxf(acc[n][0], acc[n][1]), fmaxf(acc[n][2], acc[n][3]));
      unsigned long long msk = __ballot(em > TAU);
      while (msk) {                  // near-one-hot: ~1-2 iterations
        int L = __builtin_ctzll(msk);
        msk &= msk - 1;
        float w0 = __uint_as_float(__builtin_amdgcn_readlane(__float_as_uint(acc[n][0]), L));
        float w1 = __uint_as_float(__builtin_amdgcn_readlane(__float_as_uint(acc[n][1]), L));
        float w2 = __uint_as_float(__builtin_amdgcn_readlane(__float_as_uint(acc[n][2]), L));
        float w3 = __uint_as_float(__builtin_amdgcn_readlane(__float_as_uint(acc[n][3]), L));
        float bv = blk[(size_t)(128 * h + 16 * n + (L & 15)) * 64 + lane];
        switch (L >> 4) {            // contributor's q (uniform scalar branch)
          case 0: rr[0] += w0 * bv;  rr[1] += w1 * bv;  rr[2] += w2 * bv;  rr[3] += w3 * bv;  break;
          case 1: rr[4] += w0 * bv;  rr[5] += w1 * bv;  rr[6] += w2 * bv;  rr[7] += w3 * bv;  break;
          case 2: rr[8] += w0 * bv;  rr[9] += w1 * bv;  rr[10] += w2 * bv; rr[11] += w3 * bv; break;
          default: rr[12] += w0 * bv; rr[13] += w1 * bv; rr[14] += w2 * bv; rr[15] += w3 * bv; break;
        }
      }
    }
    if (h == 0) {
      asm volatile("s_waitcnt vmcnt(0)" ::: "memory");
      __syncthreads();  // bar3: half-1 B staged
    }
  }

  // ---- final denominator + invS + penalty (closed form from S only) ----
  float invS[4];
#pragma unroll
  for (int r = 0; r < 4; ++r) {
#pragma unroll
    for (int off = 1; off <= 8; off <<= 1) sm[r] += __shfl_xor(sm[r], off, 64);
    invS[r] = 1.0f / sm[r];
  }
  float pen = 0.f;
  if (c15 == 0) {
#pragma unroll
    for (int r = 0; r < 4; ++r)
      // sum_k min(w,1-w) = 1 + [w_max>1/2](1-2*w_max), w_max = invS exactly
      pen += (invS[r] > 0.5f) ? (2.0f - 2.0f * invS[r]) : 1.0f;
  }
  pen += __shfl_xor(pen, 16, 64);   // only lanes 0,16,32,48 are nonzero
  pen += __shfl_xor(pen, 32, 64);
  if (lane == 0) atomicAdd(penAcc, pen * INV_N);

  __syncthreads();  // bar4: all B reads done -> region reusable as recon

  // ---- stage invS + recon (d = lane); readers are same-wave (lgkmcnt) ----
  if (c15 == 0) {
#pragma unroll
    for (int r = 0; r < 4; ++r)
      sMemF[WS + wave * 16 + 4 * q + r] = invS[r];
  }
#pragma unroll
  for (int pl = 0; pl < 16; ++pl)
    sMemF[WR + (wave * 16 + pl) * 68 + lane] = rr[pl];
  // wave w owns cols [128w, 128w+128) of the 8x512 strip
  float* outBase = out + (size_t)b * (512 * 512) + (size_t)(ht * 8) * 512 +
                   wave * 128;
#pragma unroll
  for (int i = 0; i < 4; ++i) {
    int f = i * 64 + lane;          // float4-chunk id in wave's 8x128 stripe
    int row = f >> 5;               // 0..7
    int cc = f & 31;                // float4 col within stripe
    int wtl = cc >> 1, hw = cc & 1;
    float4 v = *reinterpret_cast<const float4*>(
        &sMemF[WR + (wave * 16 + wtl) * 68 + row * 8 + hw * 4]);
    float is = sMemF[WS + wave * 16 + wtl];
    v.x *= is; v.y *= is; v.z *= is; v.w *= is;
    *reinterpret_cast<float4*>(outBase + row * 512 + cc * 4) = v;
  }
}

extern "C" void kernel_launch(void* const* d_in, const int* in_sizes, int n_in,
                              void* d_out, int out_size, void* d_ws, size_t ws_size,
                              hipStream_t stream) {
  const float* img = (const float*)d_in[0];   // (64,1,512,512) fp32
  const float* blk = (const float*)d_in[1];   // (256,8,8) fp32
  float* out = (float*)d_out;
  float* penSlot = out + IMG_ELEMS;

  unsigned* wsBh = (unsigned*)d_ws;           // 32 KB (pre-swizzled)
  unsigned* wsBl = wsBh + 8192;               // 32 KB (pre-swizzled)
  float* wsB2 = (float*)(wsBl + 8192);        // 1 KB (-BETA*||b||^2)

  pack_codes<<<dim3(8), dim3(256), 0, stream>>>(blk, wsBh, wsBl, wsB2);
  hipMemsetAsync(penSlot, 0, sizeof(float), stream);
  recon_kernel<<<dim3(4096), dim3(256), 0, stream>>>(img, blk, wsBh, wsBl,
                                                     wsB2, out, penSlot);
}